// Round 19
// baseline (191.269 us; speedup 1.0000x reference)
//
#include <hip/hip_runtime.h>
#include <stdint.h>

typedef __attribute__((ext_vector_type(4))) int int32x4;

#define PK_TILE_U32 131072   // one 128-row packed tile = 512 KB = 131072 u32
#define PK_TILE_B   524288

// ---------------------------------------------------------------------------
// sign_pack2: f32 -> i8 (+1/-1), blocked k-major layout:
//   [tile = row/128][chunk = k/16][row % 128][16 bytes]
// 16 lanes' frag reads = 256B contiguous -> global frag loads coalesce.
// ---------------------------------------------------------------------------
__global__ __launch_bounds__(256) void sign_pack2(const float* __restrict__ x,
                                                  const float* __restrict__ w,
                                                  uint32_t* __restrict__ xp,
                                                  uint32_t* __restrict__ wp) {
    const float* in = blockIdx.y ? w : x;
    uint32_t* outp  = blockIdx.y ? wp : xp;
    const int lane = threadIdx.x & 63;
    const int wave = (blockIdx.x * blockDim.x + threadIdx.x) >> 6;
    const int nw   = (gridDim.x * blockDim.x) >> 6;
    for (int it = wave; it < 4096 * 16; it += nw) {
        const int row = it >> 4;
        const int col = ((it & 15) << 8) + lane * 4;
        float4 v = *(const float4*)(in + (size_t)row * 4096 + col);
        uint32_t wd = (v.x > 0.f ? 1u : 0xFFu)
                    | ((v.y > 0.f ? 1u : 0xFFu) << 8)
                    | ((v.z > 0.f ? 1u : 0xFFu) << 16)
                    | ((v.w > 0.f ? 1u : 0xFFu) << 24);
        const int tile = row >> 7, rl = row & 127;
        const int chunk = col >> 4;          // k/16
        const int word  = (col >> 2) & 3;    // u32 within 16B slot
        outp[(size_t)tile * PK_TILE_U32 + chunk * 512 + rl * 4 + word] = wd;
    }
}

// ---------------------------------------------------------------------------
// i8 MFMA GEMM v11 — NO LDS: frags load straight global -> VGPR.
// R9-R18 invariant: MFMA busy (~27us) + LDS pipe busy (~25us) SUM in every
// schedule — the LDS round-trip (stage writes + ds_reads + barriers) is the
// structural serializer. But packed inputs are 16 MB each: fully L2/L3
// resident (guide m169: staging L2-fit data is pure overhead). The blocked
// k-major layout makes global frag reads coalesced (16 lanes x 16B = 256B
// segments), so LDS provides nothing.
// Per CU per 128-K-tile: L2 reads 192 KB (~1400 cyc @135 B/cyc) vs MFMA
// 2613 cyc -> MFMA-dominant 1.8x. Zero barriers: waves free-run, compiler
// pipelines loads across MFMA with counted vmcnt.
// Geometry/addressing identical data to R13 (verified exact):
// 256x256 tile, 8 waves (2Mx4N), wave tile 128x64, acc[8][4] AGPR-native.
// Per 64-k step: a[8]+b[4] loads (2 pointer bumps, imm offsets), 32 MFMA.
// A lane: tile brow*2+wr, chunk ks*4+(lane>>4), byte m*256+(lane&15)*16.
// B lane: tile bcol*2+(wc>>1), same chunking, byte (wc&1)*1024+n*256+...
// C/D: col=lane&15, row=(lane>>4)*4+reg. Grid 256 = 1 block/CU, XCD swizzle
// (16 same-brow blocks/XCD share A panels in L2).
// ---------------------------------------------------------------------------
__global__ __launch_bounds__(512) void i8_gemm11(const uint32_t* __restrict__ xp,
                                                 const uint32_t* __restrict__ wp,
                                                 float* __restrict__ out) {
    const int tid  = threadIdx.x;
    const int lane = tid & 63;
    const int wv   = tid >> 6;           // 0..7
    const int wr   = wv >> 2;            // row half (128 rows)
    const int wc   = wv & 3;             // col quarter (64 cols)

    int lid = blockIdx.x;                // bijective XCD swizzle (256%8==0)
    lid = (lid & 7) * 32 + (lid >> 3);
    const int brow = lid >> 4, bcol = lid & 15;

    // per-lane frag base addresses (advance by 8192 per 64-k step)
    const uint8_t* pA = (const uint8_t*)xp + (size_t)(brow * 2 + wr) * PK_TILE_B
                      + (lane >> 4) * 2048 + (lane & 15) * 16;
    const uint8_t* pB = (const uint8_t*)wp + (size_t)(bcol * 2 + (wc >> 1)) * PK_TILE_B
                      + (lane >> 4) * 2048 + ((wc & 1) * 64 + (lane & 15)) * 16;

    int32x4 acc[8][4];
#pragma unroll
    for (int m = 0; m < 8; ++m)
#pragma unroll
        for (int n = 0; n < 4; ++n) acc[m][n] = (int32x4){0, 0, 0, 0};

#pragma unroll 2
    for (int ks = 0; ks < 64; ++ks) {
        int32x4 a[8], b[4];
#pragma unroll
        for (int m = 0; m < 8; ++m) a[m] = *(const int32x4*)(pA + m * 256);
#pragma unroll
        for (int n = 0; n < 4; ++n) b[n] = *(const int32x4*)(pB + n * 256);
#pragma unroll
        for (int m = 0; m < 8; ++m)
#pragma unroll
            for (int n = 0; n < 4; ++n)
                acc[m][n] = __builtin_amdgcn_mfma_i32_16x16x64_i8(
                    a[m], b[n], acc[m][n], 0, 0, 0);
        pA += 8192;
        pB += 8192;
    }

    // epilogue: i32 -> f32 exact. C/D: col = lane&15, row = (lane>>4)*4 + reg
    const int orow = brow * 256 + wr * 128 + (lane >> 4) * 4;
    const int ocol = bcol * 256 + wc * 64 + (lane & 15);
#pragma unroll
    for (int m = 0; m < 8; ++m)
#pragma unroll
        for (int reg = 0; reg < 4; ++reg) {
            const size_t rb = (size_t)(orow + m * 16 + reg) * 4096 + ocol;
#pragma unroll
            for (int n = 0; n < 4; ++n)
                out[rb + n * 16] = (float)acc[m][n][reg];
        }
}

// ======================= fallback (R8 binary path) =========================
__global__ __launch_bounds__(256) void binarize64(const float* __restrict__ in,
                                                  unsigned long long* __restrict__ out,
                                                  int n64) {
    const int tid  = blockIdx.x * blockDim.x + threadIdx.x;
    const int lane = threadIdx.x & 63;
    const int wave = tid >> 6;
    const int nwav = (gridDim.x * blockDim.x) >> 6;
    for (int w = wave; w < n64; w += nwav) {
        float v = in[(size_t)w * 64 + lane];
        unsigned long long m = __ballot(v > 0.0f);
        if (lane == 0) out[w] = m;
    }
}

static __device__ __forceinline__ void pacc4(uint32_t& acc, const uint4& a, const uint4& b) {
    uint32_t t0, t1, t2, t3;
    asm("v_xor_b32 %1, %5, %9\n\t"
        "v_xor_b32 %2, %6, %10\n\t"
        "v_xor_b32 %3, %7, %11\n\t"
        "v_xor_b32 %4, %8, %12\n\t"
        "v_bcnt_u32_b32 %0, %1, %0\n\t"
        "v_bcnt_u32_b32 %0, %2, %0\n\t"
        "v_bcnt_u32_b32 %0, %3, %0\n\t"
        "v_bcnt_u32_b32 %0, %4, %0"
        : "+v"(acc), "=&v"(t0), "=&v"(t1), "=&v"(t2), "=&v"(t3)
        : "v"(a.x), "v"(a.y), "v"(a.z), "v"(a.w),
          "v"(b.x), "v"(b.y), "v"(b.z), "v"(b.w));
}

__global__ __launch_bounds__(256, 2) void xnor_gemm(const uint32_t* __restrict__ xb,
                                                    const uint32_t* __restrict__ wb,
                                                    float* __restrict__ out) {
    __shared__ uint4 lA[128 * 8];
    __shared__ uint4 lB[64 * 8];
    const int tid  = threadIdx.x;
    const int brow = blockIdx.y, bcol = blockIdx.x;
    const int tx = tid & 15, ty = tid >> 4;
    const uint4* gA = (const uint4*)xb + (size_t)(brow * 128) * 32;
    const uint4* gB = (const uint4*)wb + (size_t)(bcol * 64) * 32;
    const int sr = tid >> 3, scw = tid & 7;
    uint32_t acc[8][4];
#pragma unroll
    for (int r = 0; r < 8; ++r)
#pragma unroll
        for (int c = 0; c < 4; ++c) acc[r][c] = 0;
    const uint4* pa = lA + ty * 64;
    const uint4* pb = lB + tx * 32;
    const int ka = ty & 7, kb = tx >> 1;
    for (int ck = 0; ck < 4; ++ck) {
        if (ck) __syncthreads();
#pragma unroll
        for (int k = 0; k < 4; ++k) {
            const int r = sr + k * 32;
            lA[r * 8 + (scw ^ ((r >> 3) & 7))] = gA[(size_t)r * 32 + ck * 8 + scw];
        }
#pragma unroll
        for (int k = 0; k < 2; ++k) {
            const int r = sr + k * 32;
            lB[r * 8 + (scw ^ ((r >> 3) & 7))] = gB[(size_t)r * 32 + ck * 8 + scw];
        }
        __syncthreads();
#pragma unroll 1
        for (int j = 0; j < 8; ++j) {
            const uint4* paj = pa + (j ^ ka);
            const uint4* pbj = pb + (j ^ kb);
            uint4 a[8], b[4];
#pragma unroll
            for (int r = 0; r < 8; ++r) a[r] = paj[r * 8];
#pragma unroll
            for (int c = 0; c < 4; ++c) b[c] = pbj[c * 8];
#pragma unroll
            for (int r = 0; r < 8; ++r)
#pragma unroll
                for (int c = 0; c < 4; ++c) pacc4(acc[r][c], a[r], b[c]);
        }
    }
    const int gcol = bcol * 64 + tx * 4;
#pragma unroll
    for (int r = 0; r < 8; ++r) {
        const size_t grow = (size_t)(brow * 128 + ty * 8 + r);
        float4 o;
        o.x = (float)(4096 - 2 * (int)acc[r][0]);
        o.y = (float)(4096 - 2 * (int)acc[r][1]);
        o.z = (float)(4096 - 2 * (int)acc[r][2]);
        o.w = (float)(4096 - 2 * (int)acc[r][3]);
        *(float4*)(out + grow * 4096 + gcol) = o;
    }
}

extern "C" void kernel_launch(void* const* d_in, const int* in_sizes, int n_in,
                              void* d_out, int out_size, void* d_ws, size_t ws_size,
                              hipStream_t stream) {
    const float* x = (const float*)d_in[0];   // [4096, 4096]
    const float* W = (const float*)d_in[1];   // [4096, 4096] (out, in)
    float* out = (float*)d_out;               // [4096, 4096] f32

    if (ws_size >= 2u * 16777216u) {
        uint32_t* xp = (uint32_t*)d_ws;                 // 16 MB packed x
        uint32_t* wpk = xp + (size_t)4194304;           // 16 MB packed W
        sign_pack2<<<dim3(2048, 2), 256, 0, stream>>>(x, W, xp, wpk);
        i8_gemm11<<<256, 512, 0, stream>>>(xp, wpk, out);
    } else {
        uint32_t* xb = (uint32_t*)d_ws;
        uint32_t* wb = xb + (size_t)4096 * 128;
        const int n64 = 4096 * 4096 / 64;
        binarize64<<<2048, 256, 0, stream>>>(x, (unsigned long long*)xb, n64);
        binarize64<<<2048, 256, 0, stream>>>(W, (unsigned long long*)wb, n64);
        dim3 grid(64, 32);
        xnor_gemm<<<grid, 256, 0, stream>>>(xb, wb, out);
    }
}

// Round 20
// 100.059 us; speedup vs baseline: 1.9116x; 1.9116x over previous
//
#include <hip/hip_runtime.h>
#include <stdint.h>

typedef __attribute__((ext_vector_type(4))) int int32x4;

#define PK_TILE_U32 131072   // one 128-row packed tile = 512 KB = 131072 u32

// ---------------------------------------------------------------------------
// sign_pack2: f32 -> i8 (+1/-1), blocked k-major layout:
//   [tile = row/128][chunk = k/16][row % 128][16 bytes]
// Each 128-k K-tile of a 128-row tile is one LINEAR 16 KB block.
// BW-bound: 128 MB read + 32 MB write ≈ 27 us floor.
// ---------------------------------------------------------------------------
__global__ __launch_bounds__(256) void sign_pack2(const float* __restrict__ x,
                                                  const float* __restrict__ w,
                                                  uint32_t* __restrict__ xp,
                                                  uint32_t* __restrict__ wp) {
    const float* in = blockIdx.y ? w : x;
    uint32_t* outp  = blockIdx.y ? wp : xp;
    const int lane = threadIdx.x & 63;
    const int wave = (blockIdx.x * blockDim.x + threadIdx.x) >> 6;
    const int nw   = (gridDim.x * blockDim.x) >> 6;
    for (int it = wave; it < 4096 * 16; it += nw) {
        const int row = it >> 4;
        const int col = ((it & 15) << 8) + lane * 4;
        float4 v = *(const float4*)(in + (size_t)row * 4096 + col);
        uint32_t wd = (v.x > 0.f ? 1u : 0xFFu)
                    | ((v.y > 0.f ? 1u : 0xFFu) << 8)
                    | ((v.z > 0.f ? 1u : 0xFFu) << 16)
                    | ((v.w > 0.f ? 1u : 0xFFu) << 24);
        const int tile = row >> 7, rl = row & 127;
        const int chunk = col >> 4;          // k/16
        const int word  = (col >> 2) & 3;    // u32 within 16B slot
        outp[(size_t)tile * PK_TILE_U32 + chunk * 512 + rl * 4 + word] = wd;
    }
}

// ---------------------------------------------------------------------------
// i8 MFMA GEMM v5b — R13 (best: 70 us GEMM, 101.1 total), identity block
// mapping (no XCD swizzle). Rationale: packed operands are 32 MB = fully
// L3-resident, GEMM read BW ~1 TB/s (not HBM-bound); guide m160 measured
// the swizzle as ~2% COST in the L3-fit regime.
// Structure box (R9-R19, 11 variants): MFMA 2611 cyc/SIMD + LDS ~2300 cyc/CU
// per K-tile serialize; escapes are closed by arithmetic:
//  - 4 waves/SIMD needs <=128 regs/wave; acc alone = 128 AGPR -> dead.
//  - smaller wave tiles double LDS traffic/op -> LDS-bound at same time.
//  - bigger wave tiles: 512 regs, 1 wave/SIMD (R17: 246 us).
//  - fine phases / counted vmcnt / setprio / 32x32 shape: all null.
// Geometry: 256x256 tile, 512 thr = 8 waves (2Mx4N), wave tile 128x64,
// acc[8][4] AGPR-native; K-tile 128k; LDS 2 x 64 KB dbuf; grid 256 = 1/CU.
// Schedule: STAGE(kt+1) first, one __syncthreads per K-tile.
// Frag reads 256B-contiguous per 16 lanes (0 conflicts measured).
// A-frag row=lane&15 chunk=lane>>4; C/D col=lane&15 row=(lane>>4)*4+reg
// (all verified exact, absmax 0 across rounds).
// ---------------------------------------------------------------------------
__global__ __launch_bounds__(512) void i8_gemm5(const uint32_t* __restrict__ xp,
                                                const uint32_t* __restrict__ wp,
                                                float* __restrict__ out) {
    __shared__ uint4 ldsv[8192];   // 128 KB: buf0 @0, buf1 @65536; A @+0, B @+32768
    uint8_t* lds = (uint8_t*)ldsv;

    const int tid  = threadIdx.x;
    const int lane = tid & 63;
    const int wv   = tid >> 6;           // 0..7
    const int wr   = wv >> 2;            // row half
    const int wc   = wv & 3;             // col quarter

    const int lid  = blockIdx.x;         // identity mapping (A/B vs R13 swizzle)
    const int brow = lid >> 4, bcol = lid & 15;

    const uint8_t* gA = (const uint8_t*)(xp + (size_t)(brow * 2) * PK_TILE_U32) + tid * 16;
    const uint8_t* gB = (const uint8_t*)(wp + (size_t)(bcol * 2) * PK_TILE_U32) + tid * 16;
    const int wvo = wv * 1024;

#define GL(src, doff) __builtin_amdgcn_global_load_lds( \
        (const __attribute__((address_space(1))) uint32_t*)(src), \
        (__attribute__((address_space(3))) uint32_t*)(lds + (doff) + wvo), 16, 0, 0)

#define STAGE(kt, boff) do {                                          \
        const uint8_t* a_ = gA + (size_t)(kt) * 16384;                \
        const uint8_t* b_ = gB + (size_t)(kt) * 16384;                \
        GL(a_,                    (boff) +     0);                    \
        GL(a_ + 8192,             (boff) +  8192);                    \
        GL(a_ + 524288,           (boff) + 16384);                    \
        GL(a_ + 524288 + 8192,    (boff) + 24576);                    \
        GL(b_,                    (boff) + 32768);                    \
        GL(b_ + 8192,             (boff) + 40960);                    \
        GL(b_ + 524288,           (boff) + 49152);                    \
        GL(b_ + 524288 + 8192,    (boff) + 57344);                    \
    } while (0)

    int32x4 acc[8][4];
#pragma unroll
    for (int m = 0; m < 8; ++m)
#pragma unroll
        for (int n = 0; n < 4; ++n) acc[m][n] = (int32x4){0, 0, 0, 0};

    const int paBase = wr * 16384 + (lane >> 4) * 2048 + (lane & 15) * 16;
    const int pbBase = 32768 + (wc >> 1) * 16384 + (lane >> 4) * 2048
                     + ((wc & 1) * 64 + (lane & 15)) * 16;

    STAGE(0, 0);
    __syncthreads();

#pragma unroll 1
    for (int kt = 0; kt < 32; ++kt) {
        const int bo = (kt & 1) << 16;
        if (kt + 1 < 32) STAGE(kt + 1, bo ^ 65536);   // issue first: max cover

#pragma unroll
        for (int kk = 0; kk < 2; ++kk) {
            int32x4 a[8], b[4];
#pragma unroll
            for (int m = 0; m < 8; ++m)
                a[m] = *(const int32x4*)(lds + bo + paBase + kk * 8192 + m * 256);
#pragma unroll
            for (int n = 0; n < 4; ++n)
                b[n] = *(const int32x4*)(lds + bo + pbBase + kk * 8192 + n * 256);
#pragma unroll
            for (int m = 0; m < 8; ++m)
#pragma unroll
                for (int n = 0; n < 4; ++n)
                    acc[m][n] = __builtin_amdgcn_mfma_i32_16x16x64_i8(
                        a[m], b[n], acc[m][n], 0, 0, 0);
        }
        __syncthreads();   // one drain per K-tile
    }

    // epilogue: i32 -> f32 exact. C/D: col = lane&15, row = (lane>>4)*4 + reg
    const int orow = brow * 256 + wr * 128 + (lane >> 4) * 4;
    const int ocol = bcol * 256 + wc * 64 + (lane & 15);
#pragma unroll
    for (int m = 0; m < 8; ++m)
#pragma unroll
        for (int reg = 0; reg < 4; ++reg) {
            const size_t rb = (size_t)(orow + m * 16 + reg) * 4096 + ocol;
#pragma unroll
            for (int n = 0; n < 4; ++n)
                out[rb + n * 16] = (float)acc[m][n][reg];
        }
#undef STAGE
#undef GL
}

// ======================= fallback (R8 binary path) =========================
__global__ __launch_bounds__(256) void binarize64(const float* __restrict__ in,
                                                  unsigned long long* __restrict__ out,
                                                  int n64) {
    const int tid  = blockIdx.x * blockDim.x + threadIdx.x;
    const int lane = threadIdx.x & 63;
    const int wave = tid >> 6;
    const int nwav = (gridDim.x * blockDim.x) >> 6;
    for (int w = wave; w < n64; w += nwav) {
        float v = in[(size_t)w * 64 + lane];
        unsigned long long m = __ballot(v > 0.0f);
        if (lane == 0) out[w] = m;
    }
}

static __device__ __forceinline__ void pacc4(uint32_t& acc, const uint4& a, const uint4& b) {
    uint32_t t0, t1, t2, t3;
    asm("v_xor_b32 %1, %5, %9\n\t"
        "v_xor_b32 %2, %6, %10\n\t"
        "v_xor_b32 %3, %7, %11\n\t"
        "v_xor_b32 %4, %8, %12\n\t"
        "v_bcnt_u32_b32 %0, %1, %0\n\t"
        "v_bcnt_u32_b32 %0, %2, %0\n\t"
        "v_bcnt_u32_b32 %0, %3, %0\n\t"
        "v_bcnt_u32_b32 %0, %4, %0"
        : "+v"(acc), "=&v"(t0), "=&v"(t1), "=&v"(t2), "=&v"(t3)
        : "v"(a.x), "v"(a.y), "v"(a.z), "v"(a.w),
          "v"(b.x), "v"(b.y), "v"(b.z), "v"(b.w));
}

__global__ __launch_bounds__(256, 2) void xnor_gemm(const uint32_t* __restrict__ xb,
                                                    const uint32_t* __restrict__ wb,
                                                    float* __restrict__ out) {
    __shared__ uint4 lA[128 * 8];
    __shared__ uint4 lB[64 * 8];
    const int tid  = threadIdx.x;
    const int brow = blockIdx.y, bcol = blockIdx.x;
    const int tx = tid & 15, ty = tid >> 4;
    const uint4* gA = (const uint4*)xb + (size_t)(brow * 128) * 32;
    const uint4* gB = (const uint4*)wb + (size_t)(bcol * 64) * 32;
    const int sr = tid >> 3, scw = tid & 7;
    uint32_t acc[8][4];
#pragma unroll
    for (int r = 0; r < 8; ++r)
#pragma unroll
        for (int c = 0; c < 4; ++c) acc[r][c] = 0;
    const uint4* pa = lA + ty * 64;
    const uint4* pb = lB + tx * 32;
    const int ka = ty & 7, kb = tx >> 1;
    for (int ck = 0; ck < 4; ++ck) {
        if (ck) __syncthreads();
#pragma unroll
        for (int k = 0; k < 4; ++k) {
            const int r = sr + k * 32;
            lA[r * 8 + (scw ^ ((r >> 3) & 7))] = gA[(size_t)r * 32 + ck * 8 + scw];
        }
#pragma unroll
        for (int k = 0; k < 2; ++k) {
            const int r = sr + k * 32;
            lB[r * 8 + (scw ^ ((r >> 3) & 7))] = gB[(size_t)r * 32 + ck * 8 + scw];
        }
        __syncthreads();
#pragma unroll 1
        for (int j = 0; j < 8; ++j) {
            const uint4* paj = pa + (j ^ ka);
            const uint4* pbj = pb + (j ^ kb);
            uint4 a[8], b[4];
#pragma unroll
            for (int r = 0; r < 8; ++r) a[r] = paj[r * 8];
#pragma unroll
            for (int c = 0; c < 4; ++c) b[c] = pbj[c * 8];
#pragma unroll
            for (int r = 0; r < 8; ++r)
#pragma unroll
                for (int c = 0; c < 4; ++c) pacc4(acc[r][c], a[r], b[c]);
        }
    }
    const int gcol = bcol * 64 + tx * 4;
#pragma unroll
    for (int r = 0; r < 8; ++r) {
        const size_t grow = (size_t)(brow * 128 + ty * 8 + r);
        float4 o;
        o.x = (float)(4096 - 2 * (int)acc[r][0]);
        o.y = (float)(4096 - 2 * (int)acc[r][1]);
        o.z = (float)(4096 - 2 * (int)acc[r][2]);
        o.w = (float)(4096 - 2 * (int)acc[r][3]);
        *(float4*)(out + grow * 4096 + gcol) = o;
    }
}

extern "C" void kernel_launch(void* const* d_in, const int* in_sizes, int n_in,
                              void* d_out, int out_size, void* d_ws, size_t ws_size,
                              hipStream_t stream) {
    const float* x = (const float*)d_in[0];   // [4096, 4096]
    const float* W = (const float*)d_in[1];   // [4096, 4096] (out, in)
    float* out = (float*)d_out;               // [4096, 4096] f32

    if (ws_size >= 2u * 16777216u) {
        uint32_t* xp = (uint32_t*)d_ws;                 // 16 MB packed x
        uint32_t* wpk = xp + (size_t)4194304;           // 16 MB packed W
        sign_pack2<<<dim3(2048, 2), 256, 0, stream>>>(x, W, xp, wpk);
        i8_gemm5<<<256, 512, 0, stream>>>(xp, wpk, out);
    } else {
        uint32_t* xb = (uint32_t*)d_ws;
        uint32_t* wb = xb + (size_t)4096 * 128;
        const int n64 = 4096 * 4096 / 64;
        binarize64<<<2048, 256, 0, stream>>>(x, (unsigned long long*)xb, n64);
        binarize64<<<2048, 256, 0, stream>>>(W, (unsigned long long*)wb, n64);
        dim3 grid(64, 32);
        xnor_gemm<<<grid, 256, 0, stream>>>(xb, wb, out);
    }
}